// Round 2
// baseline (588.262 us; speedup 1.0000x reference)
//
#include <hip/hip_runtime.h>
#include <cstdint>

// Householder reflection, row-wise over [B=16384, L=4096] fp32:
//   out[b, :] = z[b, :] - 2 * v[b, :] * (v[b].z[b]) / (v[b].v[b])
//
// R2: DMA-fed pipeline. R0 (block/row, 25 waves/CU, re-read) and R1 (wave/row,
// reg-retention attempt) both plateaued at ~2.8 TB/s HBM: the per-wave
// load->wait->reduce->store phase structure chops the read stream. Here the
// read stream is decoupled from compute entirely:
//   - BLOCK=64 (one wave): butterfly-only reduction, NO barriers, so there is
//     no syncthreads-induced s_waitcnt vmcnt(0) drain anywhere in the loop.
//   - v+z row double-buffered in LDS (64 KiB -> exactly 2 blocks/CU, grid=512
//     persistent blocks x 32 rows). Staging via global_load_lds width=16:
//     no VGPRs consumed, compiler cannot rematerialize.
//   - Counted wait: s_waitcnt vmcnt(32) leaves the next row's 32 staging loads
//     (32 KB/wave, 64 KB/CU) in flight across the whole compute+store phase.
//     vmcnt(32) (not 48) also covers any compiler reordering of the 16 output
//     stores vs the staging loads: everything except the newest stage drains.
//   - Non-temporal stores keep the dead out-stream from evicting v/z in L3.

#define L 4096
#define NBLK 512   // 2 blocks/CU * 256 CU
#define SEGS 16    // 1 KiB global_load_lds segments per 16 KiB row array

typedef float f32x4 __attribute__((ext_vector_type(4)));

__global__ __launch_bounds__(64, 1) void hh_kernel(
    const float* __restrict__ v,
    const float* __restrict__ z,
    float* __restrict__ out, int B)
{
    __shared__ float vbuf[2][L];   // 32 KiB
    __shared__ float zbuf[2][L];   // 32 KiB

    const int lane = threadIdx.x & 63;
    const int bid  = blockIdx.x;
    // rows handled by this block: bid, bid+NBLK, bid+2*NBLK, ...
    const int nit = (B - bid + NBLK - 1) / NBLK;
    if (nit <= 0) return;

    // Stage one row (v half + z half) into LDS buffer `buf`.
    // LDS dest is wave-uniform base (HW adds lane*16); global src is per-lane.
    auto stage = [&](int buf, int row) {
        const float* vsrc = v + (long long)row * L + lane * 4;
        const float* zsrc = z + (long long)row * L + lane * 4;
#pragma unroll
        for (int s = 0; s < SEGS; ++s)
            __builtin_amdgcn_global_load_lds(
                (const __attribute__((address_space(1))) uint32_t*)(vsrc + s * 256),
                (__attribute__((address_space(3))) uint32_t*)&vbuf[buf][s * 256],
                16, 0, 0);
#pragma unroll
        for (int s = 0; s < SEGS; ++s)
            __builtin_amdgcn_global_load_lds(
                (const __attribute__((address_space(1))) uint32_t*)(zsrc + s * 256),
                (__attribute__((address_space(3))) uint32_t*)&zbuf[buf][s * 256],
                16, 0, 0);
    };

    stage(0, bid);  // prologue: first row in flight

    for (int it = 0; it < nit; ++it) {
        const int  cur  = it & 1;
        const bool more = (it + 1 < nit);

        // Issue next row's staging BEFORE touching current row: these 32 loads
        // remain in flight during the entire reduce + store below.
        if (more) stage(cur ^ 1, bid + (it + 1) * NBLK);

        // Wait only for the CURRENT row's staging (and anything older).
        if (more) asm volatile("s_waitcnt vmcnt(32)" ::: "memory");
        else      asm volatile("s_waitcnt vmcnt(0)"  ::: "memory");

        const f32x4* vb = (const f32x4*)vbuf[cur];
        const f32x4* zb = (const f32x4*)zbuf[cur];

        // Pass 1: dot & norm, 4 independent accumulator pairs.
        f32x4 d0 = {0,0,0,0}, d1 = {0,0,0,0}, d2 = {0,0,0,0}, d3 = {0,0,0,0};
        f32x4 n0 = {0,0,0,0}, n1 = {0,0,0,0}, n2 = {0,0,0,0}, n3 = {0,0,0,0};
#pragma unroll
        for (int i = 0; i < 16; i += 4) {
            f32x4 a0 = vb[lane + (i+0)*64], b0 = zb[lane + (i+0)*64];
            f32x4 a1 = vb[lane + (i+1)*64], b1 = zb[lane + (i+1)*64];
            f32x4 a2 = vb[lane + (i+2)*64], b2 = zb[lane + (i+2)*64];
            f32x4 a3 = vb[lane + (i+3)*64], b3 = zb[lane + (i+3)*64];
            d0 += a0*b0; n0 += a0*a0;
            d1 += a1*b1; n1 += a1*a1;
            d2 += a2*b2; n2 += a2*a2;
            d3 += a3*b3; n3 += a3*a3;
        }
        f32x4 dv = (d0 + d1) + (d2 + d3);
        f32x4 nv = (n0 + n1) + (n2 + n3);
        float dot = dv.x + dv.y + dv.z + dv.w;
        float nsq = nv.x + nv.y + nv.z + nv.w;

        // Wave-64 butterfly; wave-synchronous, no barriers.
#pragma unroll
        for (int off = 32; off > 0; off >>= 1) {
            dot += __shfl_xor(dot, off, 64);
            nsq += __shfl_xor(nsq, off, 64);
        }
        const float s = -2.0f * dot / nsq;

        // Pass 2: out = z + s*v from LDS; fire-and-forget nt stores (their
        // vmcnt slots are absorbed by the vmcnt(32) allowance next iter).
        f32x4* o4 = (f32x4*)(out + (long long)(bid + it * NBLK) * L);
#pragma unroll
        for (int i = 0; i < 16; ++i) {
            f32x4 vv = vb[lane + i*64];
            f32x4 zz = zb[lane + i*64];
            __builtin_nontemporal_store(zz + s * vv, o4 + lane + i*64);
        }
    }
}

extern "C" void kernel_launch(void* const* d_in, const int* in_sizes, int n_in,
                              void* d_out, int out_size, void* d_ws, size_t ws_size,
                              hipStream_t stream) {
    const float* v = (const float*)d_in[0];
    const float* z = (const float*)d_in[1];
    float* out = (float*)d_out;

    const int B = in_sizes[0] / L;  // 16384 rows
    hh_kernel<<<NBLK, 64, 0, stream>>>(v, z, out, B);
}